// Round 1
// baseline (9.715 us; speedup 1.0000x reference)
//
#include <hip/hip_runtime.h>

// Ragged gather: out[cu[i] + p] = req_to_token[req_pool_indices[i]][chunk_starts[i] + p]
// for p in [0, chunk_seq_lens[i]), i in [0, BATCH).
//
// Inputs (setup_inputs order):
//  d_in[0] req_to_token      int32 [POOL_SIZE=4096, MAX_CONTEXT=32768]
//  d_in[1] req_pool_indices  int32 [BATCH]
//  d_in[2] chunk_starts      int32 [BATCH]
//  d_in[3] chunk_seq_lens    int32 [BATCH]
//  d_in[4] chunk_cu_seq_lens int32 [BATCH+1]
//  d_in[5] num_chunk_tokens  int32 [1]   (unused on device; out_size == T)
// Output: int32 [T]

#define MAX_CONTEXT 32768

__global__ void ragged_gather_kernel(const int* __restrict__ req_to_token,
                                     const int* __restrict__ req_pool_indices,
                                     const int* __restrict__ chunk_starts,
                                     const int* __restrict__ chunk_cu,
                                     int* __restrict__ out) {
    const int req   = blockIdx.x;
    const int begin = chunk_cu[req];
    const int end   = chunk_cu[req + 1];
    const int len   = end - begin;

    const size_t row_off = (size_t)req_pool_indices[req] * (size_t)MAX_CONTEXT;
    const int*   src     = req_to_token + row_off + chunk_starts[req];
    int*         dst     = out + begin;

    const int stride = blockDim.x * gridDim.y;
    for (int p = threadIdx.x + blockIdx.y * blockDim.x; p < len; p += stride) {
        dst[p] = src[p];
    }
}

extern "C" void kernel_launch(void* const* d_in, const int* in_sizes, int n_in,
                              void* d_out, int out_size, void* d_ws, size_t ws_size,
                              hipStream_t stream) {
    const int* req_to_token     = (const int*)d_in[0];
    const int* req_pool_indices = (const int*)d_in[1];
    const int* chunk_starts     = (const int*)d_in[2];
    const int* chunk_cu         = (const int*)d_in[4];
    int*       out              = (int*)d_out;

    const int batch = in_sizes[1];  // 64

    dim3 grid(batch, 8, 1);         // 512 blocks; each request split across 8 blocks
    dim3 block(256, 1, 1);
    ragged_gather_kernel<<<grid, block, 0, stream>>>(
        req_to_token, req_pool_indices, chunk_starts, chunk_cu, out);
}